// Round 1
// 166.778 us; speedup vs baseline: 1.1263x; 1.1263x over previous
//
#include <hip/hip_runtime.h>

// ---------------------------------------------------------------------------
// GMMConv forward — int8-gather, MLP edition:
//  0) convert_W: Wp[j'][k]=f16(W_fc[((j'&3)<<6)|(j'>>2)][k]) into a 128 KB
//     overlay at the start of d_out (edge rewrites all of d_out afterwards).
//  1) gemm_fused: f16 MFMA (A staged fp32->f16 in LDS, B-tiles DMA'd from
//     L2-resident Wp). Epilogue quantizes acc to i8 with per-(row,64-col)
//     scale; transposed i8 store; scales (A/127^2) to sc[N][4].
//  2) edge_aggregate (REWRITTEN): still one wave per dst node (CSR order, no
//     atomics), but register-only and wide:
//       - lane l gathers int4 (16 B = 4 features x 4 k) of edge l>>4: one
//         dwordx4 instruction covers FOUR edge rows (1 KB/wave);
//       - 16-edge chunks fully unrolled with clamped tail (dead slots re-read
//         a hot row, g=0) -> ~13 loads in flight per chunk, no branches;
//       - gaussians computed once per edge by lane (ec+fo), bpermute-broadcast
//         (4x less exp work than per-group recompute);
//       - no LDS / fences -> compiler can pipeline across chunks.
//     Rationale: R9 counters showed VALUBusy 35%, HBM 24%, occupancy 50% —
//     latency-bound, not fabric-bound; breadth of outstanding gathers is the
//     lever, bytes stay 272/edge.
//  Precision: unchanged quantization pipeline (i8 per-group, g*127) ->
//  absmax ~0.6-1.0 vs threshold 2.19.
// ---------------------------------------------------------------------------

typedef _Float16 f16;
typedef __attribute__((ext_vector_type(4))) _Float16 f16x4;
typedef __attribute__((ext_vector_type(8))) _Float16 f16x8;
typedef __attribute__((ext_vector_type(4))) float f32x4;

__device__ inline f16x4 cvt4h(float4 v) {
    f16x4 h;
    h.x = (f16)v.x; h.y = (f16)v.y; h.z = (f16)v.z; h.w = (f16)v.w;
    return h;
}

__device__ inline int dot4_i8(int a, int b) {
#if __has_builtin(__builtin_amdgcn_sdot4)
    return __builtin_amdgcn_sdot4(a, b, 0, false);
#else
    return (int)(char)(a)       * (int)(char)(b)
         + (int)(char)(a >> 8)  * (int)(char)(b >> 8)
         + (int)(char)(a >> 16) * (int)(char)(b >> 16)
         + (int)(char)(a >> 24) * (int)(char)(b >> 24);
#endif
}

// W_fc fp32 [256][256] -> Wp f16 [256][256] with permuted rows.
__global__ __launch_bounds__(256) void convert_W(
    const float* __restrict__ W, f16* __restrict__ Wp)
{
    const int gid = blockIdx.x * 256 + threadIdx.x;   // 64 blocks -> 16384
    const int jp = gid >> 6, k4 = gid & 63;
    const int wrow = ((jp & 3) << 6) | (jp >> 2);
    reinterpret_cast<f16x4*>(Wp)[jp * 64 + k4] =
        cvt4h(reinterpret_cast<const float4*>(W)[wrow * 64 + k4]);
}

#define ASTRIDE 264                 // f16 per A-row in LDS (+8 pad)
#define AS_BYTES (64 * ASTRIDE * 2) // 33792, 16B aligned

// nfq[m][jp] = i8 quant of sum_k f16(feat[m][k]) * Wp[jp][k]
// sc[m][g]   = groupAbsmax / 127^2 for col group g = jp>>6
__global__ __launch_bounds__(256) void gemm_fused(
    const float* __restrict__ feat,   // fp32 [M][256]
    const f16* __restrict__ Wp,       // f16 [256][256] permuted rows
    char* __restrict__ nfq,           // i8 [M][256]
    float* __restrict__ sc,           // f32 [M][4]
    int M)
{
    __shared__ char smem[AS_BYTES + 256 * 32 * 2];  // As 33 KB + Bs/qt 16 KB
    f16* As = (f16*)smem;
    f16* Bs = (f16*)(smem + AS_BYTES);
    char* qt = smem + AS_BYTES;       // reuses Bs region in the epilogue
    const int t    = threadIdx.x;
    const int lane = t & 63;
    const int wave = t >> 6;
    const int bm   = blockIdx.x * 64;
    const int l16  = lane & 15;
    const int quad = lane >> 4;
    const int wn   = wave * 64;

    size_t bsrc[4];
#pragma unroll
    for (int j = 0; j < 4; ++j)
        bsrc[j] = (size_t)(wave * 64 + j * 16 + (lane >> 2)) * 256 + (lane & 3) * 8;

    typedef __attribute__((address_space(3))) void lds_t;
    typedef const __attribute__((address_space(1))) void gm_t;

    // kick off B DMA for k0=0, then stage A (fp32->f16) while it flies
#pragma unroll
    for (int j = 0; j < 4; ++j)
        __builtin_amdgcn_global_load_lds((gm_t*)(Wp + bsrc[j]),
            (lds_t*)(Bs + (wave * 4 + j) * 512), 16, 0, 0);

#pragma unroll
    for (int it = 0; it < 8; ++it) {
        const int flat = it * 2048 + t * 8;
        const int row  = flat >> 8;              // 0..63
        const int koff = flat & 255;
        const float* src = feat + (size_t)min(bm + row, M - 1) * 256 + koff;
        const float4 a0 = *reinterpret_cast<const float4*>(src);
        const float4 a1 = *reinterpret_cast<const float4*>(src + 4);
        *reinterpret_cast<f16x4*>(&As[row * ASTRIDE + koff])     = cvt4h(a0);
        *reinterpret_cast<f16x4*>(&As[row * ASTRIDE + koff + 4]) = cvt4h(a1);
    }

    f32x4 acc[4][4];
#pragma unroll
    for (int mi = 0; mi < 4; ++mi)
#pragma unroll
        for (int ni = 0; ni < 4; ++ni)
            acc[mi][ni] = (f32x4){0.f, 0.f, 0.f, 0.f};

    for (int ki = 0; ki < 8; ++ki) {
        __syncthreads();                         // Bs(ki) + As ready

        f16x8 af[4], bfr[4];
#pragma unroll
        for (int mi = 0; mi < 4; ++mi)
            af[mi] = *reinterpret_cast<const f16x8*>(
                &As[(mi * 16 + l16) * ASTRIDE + ki * 32 + quad * 8]);
#pragma unroll
        for (int ni = 0; ni < 4; ++ni)
            bfr[ni] = *reinterpret_cast<const f16x8*>(
                &Bs[(wn + ni * 16 + l16) * 32 + quad * 8]);

        __syncthreads();                         // all waves done reading Bs
        if (ki < 7) {
            const int k0 = (ki + 1) * 32;
#pragma unroll
            for (int j = 0; j < 4; ++j)
                __builtin_amdgcn_global_load_lds((gm_t*)(Wp + bsrc[j] + k0),
                    (lds_t*)(Bs + (wave * 4 + j) * 512), 16, 0, 0);
        }
#pragma unroll
        for (int mi = 0; mi < 4; ++mi)
#pragma unroll
            for (int ni = 0; ni < 4; ++ni)
                acc[mi][ni] = __builtin_amdgcn_mfma_f32_16x16x32_f16(
                    af[mi], bfr[ni], acc[mi][ni], 0, 0, 0);
    }
    // After the ki=7 second barrier: no more Bs reads anywhere -> qt can
    // safely overwrite the Bs region (MFMA/epilogue touch registers only).

    // quantize: per (row, this wave's 64 cols) absmax
    // C/D layout: col = lane&15, row = quad*4 + reg  [m89; dtype-independent]
#pragma unroll
    for (int mi = 0; mi < 4; ++mi) {
#pragma unroll
        for (int r = 0; r < 4; ++r) {
            float am = 0.f;
#pragma unroll
            for (int ni = 0; ni < 4; ++ni)
                am = fmaxf(am, fabsf(acc[mi][ni][r]));
            am = fmaxf(am, __shfl_xor(am, 1));   // reduce over l16 (same quad)
            am = fmaxf(am, __shfl_xor(am, 2));
            am = fmaxf(am, __shfl_xor(am, 4));
            am = fmaxf(am, __shfl_xor(am, 8));
            const float sinv = am > 0.f ? 127.f / am : 0.f;
            const int rl = mi * 16 + quad * 4 + r;
#pragma unroll
            for (int ni = 0; ni < 4; ++ni)
                qt[rl * 256 + wn + ni * 16 + l16] =
                    (char)(int)__builtin_rintf(acc[mi][ni][r] * sinv);
            if (l16 == 0) {
                const int row = bm + rl;
                if (row < M) sc[row * 4 + wave] = am * (1.f / 16129.f);
            }
        }
    }
    __syncthreads();

    // coalesced i8 store: thread t -> row t>>2, 64 B chunk (t&3)
    {
        const int rl  = t >> 2;
        const int co  = (t & 3) * 64;
        const int row = bm + rl;
        if (row < M) {
            const int4* s4 = reinterpret_cast<const int4*>(qt + rl * 256 + co);
            int4* d4 = reinterpret_cast<int4*>(nfq + (size_t)row * 256 + co);
#pragma unroll
            for (int j = 0; j < 4; ++j) d4[j] = s4[j];
        }
    }
}

// One wave per destination node. Register-only, wide-MLP aggregation:
//   lane l = (eg = l>>4 : edge slot in group-of-4, fo = l&15 : feature quad).
//   Per 16-edge chunk: 4 groups x {int4 nfq gather (4 edge rows / instr),
//   scale dword}, gaussians computed once per edge by lane fo and
//   bpermute-broadcast. No LDS, no fences, no branches inside the chunk.
__global__ __launch_bounds__(128) void edge_aggregate(
    const int* __restrict__ rowptr,
    const int* __restrict__ colind,
    const float* __restrict__ pseudo,   // [E][2]
    const char* __restrict__ nfq,       // i8 [N][256] permuted [f*4+k]
    const float* __restrict__ sc,       // f32 [N][4] group scales
    const float* __restrict__ mu,
    const float* __restrict__ inv_sigma,
    const float* __restrict__ bias,
    float* __restrict__ out,            // [N][64]
    int N)
{
    const int wave = threadIdx.x >> 6;
    const int lane = threadIdx.x & 63;
    const int node = blockIdx.x * 2 + wave;
    if (node >= N) return;              // wave-uniform

    const int fo = lane & 15;           // feature quad: f = 4*fo + r
    const int eg = lane >> 4;           // edge slot within a group of 4
    const int qoff = fo << 4;           // byte offset into a 256 B nfq row
    const int goff = fo >> 2;           // scale group = f>>4

    // per-kernel constants; fold -0.5 and log2(e) into the sigma scales so
    // the gaussian is a single exp2
    float mxk[4], myk[4], cxk[4], cyk[4];
#pragma unroll
    for (int k = 0; k < 4; ++k) {
        mxk[k] = mu[2 * k];
        myk[k] = mu[2 * k + 1];
        const float a = inv_sigma[2 * k], b = inv_sigma[2 * k + 1];
        const float c = -0.5f * 1.4426950408889634f;
        cxk[k] = c * a * a;
        cyk[k] = c * b * b;
    }

    const int e0 = rowptr[node];
    const int e1 = rowptr[node + 1];

    float acc0 = 0.f, acc1 = 0.f, acc2 = 0.f, acc3 = 0.f;

    for (int ec = e0; ec < e1; ec += 16) {
        // ---- distributed gaussian: lane fo owns edge ec+fo (clamped tail)
        const int exm = ec + fo;
        const bool gv = exm < e1;
        const int ex  = gv ? exm : e1 - 1;
        const float2 p = *reinterpret_cast<const float2*>(pseudo + 2 * (size_t)ex);
        int gpk = 0;
#pragma unroll
        for (int k = 0; k < 4; ++k) {
            const float dx = p.x - mxk[k], dy = p.y - myk[k];
            const float g = exp2f(dx * dx * cxk[k] + dy * dy * cyk[k]);
            gpk |= ((int)(g * 127.f + 0.5f)) << (8 * k);
        }
        if (!gv) gpk = 0;               // dead slot contributes nothing

        // ---- 4 groups of 4 edges: all loads issued back-to-back
        int4  q[4];
        float s[4];
        int   gq[4];
#pragma unroll
        for (int gi = 0; gi < 4; ++gi) {
            const int ei = min(ec + gi * 4 + eg, e1 - 1);   // clamped: hot row
            const int c  = colind[ei];
            q[gi]  = *reinterpret_cast<const int4*>(
                         nfq + ((size_t)c << 8) + qoff);
            s[gi]  = sc[c * 4 + goff];
            gq[gi] = __shfl(gpk, gi * 4 + eg);  // gaussian of edge gi*4+eg
        }
#pragma unroll
        for (int gi = 0; gi < 4; ++gi) {
            acc0 = fmaf(s[gi], (float)dot4_i8(q[gi].x, gq[gi]), acc0);
            acc1 = fmaf(s[gi], (float)dot4_i8(q[gi].y, gq[gi]), acc1);
            acc2 = fmaf(s[gi], (float)dot4_i8(q[gi].z, gq[gi]), acc2);
            acc3 = fmaf(s[gi], (float)dot4_i8(q[gi].w, gq[gi]), acc3);
        }
    }

    // reduce the 4 edge slots (lanes with equal fo): xor 16 then 32
    acc0 += __shfl_xor(acc0, 16); acc0 += __shfl_xor(acc0, 32);
    acc1 += __shfl_xor(acc1, 16); acc1 += __shfl_xor(acc1, 32);
    acc2 += __shfl_xor(acc2, 16); acc2 += __shfl_xor(acc2, 32);
    acc3 += __shfl_xor(acc3, 16); acc3 += __shfl_xor(acc3, 32);

    if (lane < 16) {
        const float4 b4 = reinterpret_cast<const float4*>(bias)[fo];
        float4 o;
        o.x = acc0 + b4.x;
        o.y = acc1 + b4.y;
        o.z = acc2 + b4.z;
        o.w = acc3 + b4.w;
        reinterpret_cast<float4*>(out + ((size_t)node << 6))[fo] = o;
    }
}

extern "C" void kernel_launch(void* const* d_in, const int* in_sizes, int n_in,
                              void* d_out, int out_size, void* d_ws, size_t ws_size,
                              hipStream_t stream)
{
    const int*   rowptr    = (const int*)d_in[0];
    const int*   colind    = (const int*)d_in[1];
    // d_in[2] colptr, d_in[3] rowind, d_in[4] permute: inert in forward math
    const float* feat      = (const float*)d_in[5];
    const float* pseudo    = (const float*)d_in[6];
    const float* W_fc      = (const float*)d_in[7];
    const float* mu        = (const float*)d_in[8];
    const float* inv_sigma = (const float*)d_in[9];
    const float* bias      = (const float*)d_in[10];
    float* out = (float*)d_out;

    const int N = in_sizes[0] - 1;        // 50000
    char*  nfq = (char*)d_ws;             // i8 [N][256] = 12.8 MB
    float* sc  = (float*)(nfq + (size_t)N * 256);  // f32 [N][4] = 0.8 MB
    f16*   Wp  = (f16*)d_out;             // 128 KB overlay; edge rewrites
                                          // all of d_out afterwards

    hipLaunchKernelGGL(convert_W, dim3(64), dim3(256), 0, stream, W_fc, Wp);

    hipLaunchKernelGGL(gemm_fused, dim3((N + 63) / 64), dim3(256), 0, stream,
                       feat, Wp, nfq, sc, N);

    hipLaunchKernelGGL(edge_aggregate, dim3((N + 1) / 2), dim3(128), 0, stream,
                       rowptr, colind, pseudo, nfq, sc, mu, inv_sigma, bias, out, N);
}

// Round 3
// 165.821 us; speedup vs baseline: 1.1328x; 1.0058x over previous
//
#include <hip/hip_runtime.h>

// ---------------------------------------------------------------------------
// GMMConv forward — int8-gather, cross-node-pipelined edition (v3 resubmit;
// R2 bench was an infra failure: container died before pytest, no counters).
//  0) convert_W: Wp[j'][k]=f16(W_fc[((j'&3)<<6)|(j'>>2)][k]) into a 128 KB
//     overlay at the start of d_out (edge rewrites all of d_out afterwards).
//  1) gemm_fused: f16 MFMA (A staged fp32->f16 in LDS, B-tiles DMA'd from
//     L2-resident Wp). Epilogue quantizes acc to i8 with per-(row,64-col)
//     scale; transposed i8 store; scales (A/127^2) to sc[N][4].
//  2) edge_aggregate (v3): R1 counters (VALUBusy 55%, HBM 33%, occ 50%,
//     41 us) show the cost is the PER-NODE serial miss chain (rowptr ->
//     colind -> gather), ~3.4 us/node vs ~0.3 us of work, at mean degree 16
//     (1.5 chunks). v3 overlaps chains ACROSS nodes:
//       - 2 nodes per wave: both nodes' first-chunk colind+pseudo issued up
//         front; node b's chain hides under node a's dots;
//       - 256-thread blocks (8 nodes/block): 25000 -> 6250 blocks;
//       - one colind load/chunk + shfl broadcast (was 4 redundant loads);
//       - in-loop prefetch of next chunk's colind/pseudo/gaussians;
//       - gathers issued before prefetch VALU, dots after (vmcnt in-order
//         lets dots run while next chunk's pseudo flies).
//  Precision: unchanged quantization pipeline (i8 per-group, g*127) ->
//  absmax ~0.6 vs threshold 2.19.
// ---------------------------------------------------------------------------

typedef _Float16 f16;
typedef __attribute__((ext_vector_type(4))) _Float16 f16x4;
typedef __attribute__((ext_vector_type(8))) _Float16 f16x8;
typedef __attribute__((ext_vector_type(4))) float f32x4;

__device__ inline f16x4 cvt4h(float4 v) {
    f16x4 h;
    h.x = (f16)v.x; h.y = (f16)v.y; h.z = (f16)v.z; h.w = (f16)v.w;
    return h;
}

__device__ inline int dot4_i8(int a, int b) {
#if __has_builtin(__builtin_amdgcn_sdot4)
    return __builtin_amdgcn_sdot4(a, b, 0, false);
#else
    return (int)(char)(a)       * (int)(char)(b)
         + (int)(char)(a >> 8)  * (int)(char)(b >> 8)
         + (int)(char)(a >> 16) * (int)(char)(b >> 16)
         + (int)(char)(a >> 24) * (int)(char)(b >> 24);
#endif
}

// W_fc fp32 [256][256] -> Wp f16 [256][256] with permuted rows.
__global__ __launch_bounds__(256) void convert_W(
    const float* __restrict__ W, f16* __restrict__ Wp)
{
    const int gid = blockIdx.x * 256 + threadIdx.x;   // 64 blocks -> 16384
    const int jp = gid >> 6, k4 = gid & 63;
    const int wrow = ((jp & 3) << 6) | (jp >> 2);
    reinterpret_cast<f16x4*>(Wp)[jp * 64 + k4] =
        cvt4h(reinterpret_cast<const float4*>(W)[wrow * 64 + k4]);
}

#define ASTRIDE 264                 // f16 per A-row in LDS (+8 pad)
#define AS_BYTES (64 * ASTRIDE * 2) // 33792, 16B aligned

// nfq[m][jp] = i8 quant of sum_k f16(feat[m][k]) * Wp[jp][k]
// sc[m][g]   = groupAbsmax / 127^2 for col group g = jp>>6
__global__ __launch_bounds__(256) void gemm_fused(
    const float* __restrict__ feat,   // fp32 [M][256]
    const f16* __restrict__ Wp,       // f16 [256][256] permuted rows
    char* __restrict__ nfq,           // i8 [M][256]
    float* __restrict__ sc,           // f32 [M][4]
    int M)
{
    __shared__ char smem[AS_BYTES + 256 * 32 * 2];  // As 33 KB + Bs/qt 16 KB
    f16* As = (f16*)smem;
    f16* Bs = (f16*)(smem + AS_BYTES);
    char* qt = smem + AS_BYTES;       // reuses Bs region in the epilogue
    const int t    = threadIdx.x;
    const int lane = t & 63;
    const int wave = t >> 6;
    const int bm   = blockIdx.x * 64;
    const int l16  = lane & 15;
    const int quad = lane >> 4;
    const int wn   = wave * 64;

    size_t bsrc[4];
#pragma unroll
    for (int j = 0; j < 4; ++j)
        bsrc[j] = (size_t)(wave * 64 + j * 16 + (lane >> 2)) * 256 + (lane & 3) * 8;

    typedef __attribute__((address_space(3))) void lds_t;
    typedef const __attribute__((address_space(1))) void gm_t;

    // kick off B DMA for k0=0, then stage A (fp32->f16) while it flies
#pragma unroll
    for (int j = 0; j < 4; ++j)
        __builtin_amdgcn_global_load_lds((gm_t*)(Wp + bsrc[j]),
            (lds_t*)(Bs + (wave * 4 + j) * 512), 16, 0, 0);

#pragma unroll
    for (int it = 0; it < 8; ++it) {
        const int flat = it * 2048 + t * 8;
        const int row  = flat >> 8;              // 0..63
        const int koff = flat & 255;
        const float* src = feat + (size_t)min(bm + row, M - 1) * 256 + koff;
        const float4 a0 = *reinterpret_cast<const float4*>(src);
        const float4 a1 = *reinterpret_cast<const float4*>(src + 4);
        *reinterpret_cast<f16x4*>(&As[row * ASTRIDE + koff])     = cvt4h(a0);
        *reinterpret_cast<f16x4*>(&As[row * ASTRIDE + koff + 4]) = cvt4h(a1);
    }

    f32x4 acc[4][4];
#pragma unroll
    for (int mi = 0; mi < 4; ++mi)
#pragma unroll
        for (int ni = 0; ni < 4; ++ni)
            acc[mi][ni] = (f32x4){0.f, 0.f, 0.f, 0.f};

    for (int ki = 0; ki < 8; ++ki) {
        __syncthreads();                         // Bs(ki) + As ready

        f16x8 af[4], bfr[4];
#pragma unroll
        for (int mi = 0; mi < 4; ++mi)
            af[mi] = *reinterpret_cast<const f16x8*>(
                &As[(mi * 16 + l16) * ASTRIDE + ki * 32 + quad * 8]);
#pragma unroll
        for (int ni = 0; ni < 4; ++ni)
            bfr[ni] = *reinterpret_cast<const f16x8*>(
                &Bs[(wn + ni * 16 + l16) * 32 + quad * 8]);

        __syncthreads();                         // all waves done reading Bs
        if (ki < 7) {
            const int k0 = (ki + 1) * 32;
#pragma unroll
            for (int j = 0; j < 4; ++j)
                __builtin_amdgcn_global_load_lds((gm_t*)(Wp + bsrc[j] + k0),
                    (lds_t*)(Bs + (wave * 4 + j) * 512), 16, 0, 0);
        }
#pragma unroll
        for (int mi = 0; mi < 4; ++mi)
#pragma unroll
            for (int ni = 0; ni < 4; ++ni)
                acc[mi][ni] = __builtin_amdgcn_mfma_f32_16x16x32_f16(
                    af[mi], bfr[ni], acc[mi][ni], 0, 0, 0);
    }
    // After the ki=7 second barrier: no more Bs reads anywhere -> qt can
    // safely overwrite the Bs region (MFMA/epilogue touch registers only).

    // quantize: per (row, this wave's 64 cols) absmax
    // C/D layout: col = lane&15, row = quad*4 + reg  [m89; dtype-independent]
#pragma unroll
    for (int mi = 0; mi < 4; ++mi) {
#pragma unroll
        for (int r = 0; r < 4; ++r) {
            float am = 0.f;
#pragma unroll
            for (int ni = 0; ni < 4; ++ni)
                am = fmaxf(am, fabsf(acc[mi][ni][r]));
            am = fmaxf(am, __shfl_xor(am, 1));   // reduce over l16 (same quad)
            am = fmaxf(am, __shfl_xor(am, 2));
            am = fmaxf(am, __shfl_xor(am, 4));
            am = fmaxf(am, __shfl_xor(am, 8));
            const float sinv = am > 0.f ? 127.f / am : 0.f;
            const int rl = mi * 16 + quad * 4 + r;
#pragma unroll
            for (int ni = 0; ni < 4; ++ni)
                qt[rl * 256 + wn + ni * 16 + l16] =
                    (char)(int)__builtin_rintf(acc[mi][ni][r] * sinv);
            if (l16 == 0) {
                const int row = bm + rl;
                if (row < M) sc[row * 4 + wave] = am * (1.f / 16129.f);
            }
        }
    }
    __syncthreads();

    // coalesced i8 store: thread t -> row t>>2, 64 B chunk (t&3)
    {
        const int rl  = t >> 2;
        const int co  = (t & 3) * 64;
        const int row = bm + rl;
        if (row < M) {
            const int4* s4 = reinterpret_cast<const int4*>(qt + rl * 256 + co);
            int4* d4 = reinterpret_cast<int4*>(nfq + (size_t)row * 256 + co);
#pragma unroll
            for (int j = 0; j < 4; ++j) d4[j] = s4[j];
        }
    }
}

// Two dst nodes per wave, cross-node pipelined. lane = (eg = l>>4 : edge slot
// in group-of-4, fo = l&15 : feature quad). Per 16-edge chunk: one clamped
// colind load (slot fo) + shfl broadcast, gaussians computed once per edge by
// lane fo, 4x int4 nfq gathers (4 edge rows / instr), per-edge scale, sdot4.
// Node b's first-chunk colind/pseudo issued before node a's dots.
__global__ __launch_bounds__(256) void edge_aggregate(
    const int* __restrict__ rowptr,
    const int* __restrict__ colind,
    const float* __restrict__ pseudo,   // [E][2]
    const char* __restrict__ nfq,       // i8 [N][256] permuted [f*4+k]
    const float* __restrict__ sc,       // f32 [N][4] group scales
    const float* __restrict__ mu,
    const float* __restrict__ inv_sigma,
    const float* __restrict__ bias,
    float* __restrict__ out,            // [N][64]
    int N)
{
    const int lane = threadIdx.x & 63;
    const int wid  = blockIdx.x * 4 + (threadIdx.x >> 6);
    const int na   = wid * 2;
    if (na >= N) return;                // wave-uniform; no barriers below
    const int nb   = na + 1;
    const bool hb  = nb < N;

    const int fo   = lane & 15;         // feature quad: f = 4*fo + r
    const int eg   = lane >> 4;         // edge slot within a group of 4
    const int qoff = fo << 4;           // byte offset into a 256 B nfq row
    const int goff = fo >> 2;           // scale group = f>>4

    // per-kernel constants; fold -0.5 and log2(e) into the sigma scales so
    // the gaussian is a single exp2
    float mxk[4], myk[4], cxk[4], cyk[4];
#pragma unroll
    for (int k = 0; k < 4; ++k) {
        mxk[k] = mu[2 * k];
        myk[k] = mu[2 * k + 1];
        const float a = inv_sigma[2 * k], b = inv_sigma[2 * k + 1];
        const float c = -0.5f * 1.4426950408889634f;
        cxk[k] = c * a * a;
        cyk[k] = c * b * b;
    }

    // gaussian pack for the chunk at ec (lane fo owns edge ec+fo, clamped)
    auto gpack = [&](int ec, int e0, int e1) -> int {
        const int exm = ec + fo;
        const bool gv = exm < e1;
        const int safe = (e1 > e0) ? (e1 - 1) : 0;
        const int ex  = gv ? exm : safe;
        const float2 p = *reinterpret_cast<const float2*>(pseudo + 2 * (size_t)ex);
        int gp = 0;
#pragma unroll
        for (int k = 0; k < 4; ++k) {
            const float dx = p.x - mxk[k], dy = p.y - myk[k];
            const float g = exp2f(fmaf(dy * dy, cyk[k], dx * dx * cxk[k]));
            gp |= ((int)(g * 127.f + 0.5f)) << (8 * k);
        }
        return gv ? gp : 0;
    };

    const int ea0 = rowptr[na];
    const int ea1 = rowptr[na + 1];
    const int eb0 = ea1;
    const int eb1 = hb ? rowptr[nb + 1] : ea1;

    // ---- stage BOTH nodes' first chunks up front (independent loads)
    const int safea = (ea1 > ea0) ? (ea1 - 1) : 0;
    int cfo_a = colind[min(ea0 + fo, safea)];
    int cfo_b = 0, gpk_b = 0;
    if (hb) {
        const int safeb = (eb1 > eb0) ? (eb1 - 1) : 0;
        cfo_b = colind[min(eb0 + fo, safeb)];
        gpk_b = gpack(eb0, eb0, eb1);
    }
    int gpk_a = gpack(ea0, ea0, ea1);

    // ---- node a
    float a0 = 0.f, a1 = 0.f, a2 = 0.f, a3 = 0.f;
    {
        int gpk = gpk_a, cfo = cfo_a;
        for (int ec = ea0; ec < ea1; ec += 16) {
            // issue this chunk's gathers first (c arrived last iteration)
            int4  q[4];
            float s[4];
            int   gq[4];
#pragma unroll
            for (int gi = 0; gi < 4; ++gi) {
                const int c = __shfl(cfo, gi * 4 + eg);
                q[gi]  = *reinterpret_cast<const int4*>(
                             nfq + ((size_t)c << 8) + qoff);
                s[gi]  = sc[c * 4 + goff];
                gq[gi] = __shfl(gpk, gi * 4 + eg);
            }
            // prefetch next chunk (loads fly under the dots below)
            const int ecn = ec + 16;
            int gpk_n = 0, cfo_n = cfo;
            if (ecn < ea1) {
                cfo_n = colind[min(ecn + fo, ea1 - 1)];
                gpk_n = gpack(ecn, ea0, ea1);
            }
#pragma unroll
            for (int gi = 0; gi < 4; ++gi) {
                a0 = fmaf(s[gi], (float)dot4_i8(q[gi].x, gq[gi]), a0);
                a1 = fmaf(s[gi], (float)dot4_i8(q[gi].y, gq[gi]), a1);
                a2 = fmaf(s[gi], (float)dot4_i8(q[gi].z, gq[gi]), a2);
                a3 = fmaf(s[gi], (float)dot4_i8(q[gi].w, gq[gi]), a3);
            }
            gpk = gpk_n; cfo = cfo_n;
        }
    }
    // reduce over the 4 edge slots and store node a
    a0 += __shfl_xor(a0, 16); a0 += __shfl_xor(a0, 32);
    a1 += __shfl_xor(a1, 16); a1 += __shfl_xor(a1, 32);
    a2 += __shfl_xor(a2, 16); a2 += __shfl_xor(a2, 32);
    a3 += __shfl_xor(a3, 16); a3 += __shfl_xor(a3, 32);
    if (lane < 16) {
        const float4 b4 = reinterpret_cast<const float4*>(bias)[fo];
        float4 o;
        o.x = a0 + b4.x; o.y = a1 + b4.y; o.z = a2 + b4.z; o.w = a3 + b4.w;
        reinterpret_cast<float4*>(out + ((size_t)na << 6))[fo] = o;
    }

    // ---- node b (first chunk's colind/pseudo already resident)
    if (!hb) return;
    float b0 = 0.f, b1 = 0.f, b2 = 0.f, b3 = 0.f;
    {
        int gpk = gpk_b, cfo = cfo_b;
        for (int ec = eb0; ec < eb1; ec += 16) {
            int4  q[4];
            float s[4];
            int   gq[4];
#pragma unroll
            for (int gi = 0; gi < 4; ++gi) {
                const int c = __shfl(cfo, gi * 4 + eg);
                q[gi]  = *reinterpret_cast<const int4*>(
                             nfq + ((size_t)c << 8) + qoff);
                s[gi]  = sc[c * 4 + goff];
                gq[gi] = __shfl(gpk, gi * 4 + eg);
            }
            const int ecn = ec + 16;
            int gpk_n = 0, cfo_n = cfo;
            if (ecn < eb1) {
                cfo_n = colind[min(ecn + fo, eb1 - 1)];
                gpk_n = gpack(ecn, eb0, eb1);
            }
#pragma unroll
            for (int gi = 0; gi < 4; ++gi) {
                b0 = fmaf(s[gi], (float)dot4_i8(q[gi].x, gq[gi]), b0);
                b1 = fmaf(s[gi], (float)dot4_i8(q[gi].y, gq[gi]), b1);
                b2 = fmaf(s[gi], (float)dot4_i8(q[gi].z, gq[gi]), b2);
                b3 = fmaf(s[gi], (float)dot4_i8(q[gi].w, gq[gi]), b3);
            }
            gpk = gpk_n; cfo = cfo_n;
        }
    }
    b0 += __shfl_xor(b0, 16); b0 += __shfl_xor(b0, 32);
    b1 += __shfl_xor(b1, 16); b1 += __shfl_xor(b1, 32);
    b2 += __shfl_xor(b2, 16); b2 += __shfl_xor(b2, 32);
    b3 += __shfl_xor(b3, 16); b3 += __shfl_xor(b3, 32);
    if (lane < 16) {
        const float4 b4 = reinterpret_cast<const float4*>(bias)[fo];
        float4 o;
        o.x = b0 + b4.x; o.y = b1 + b4.y; o.z = b2 + b4.z; o.w = b3 + b4.w;
        reinterpret_cast<float4*>(out + ((size_t)nb << 6))[fo] = o;
    }
}

extern "C" void kernel_launch(void* const* d_in, const int* in_sizes, int n_in,
                              void* d_out, int out_size, void* d_ws, size_t ws_size,
                              hipStream_t stream)
{
    const int*   rowptr    = (const int*)d_in[0];
    const int*   colind    = (const int*)d_in[1];
    // d_in[2] colptr, d_in[3] rowind, d_in[4] permute: inert in forward math
    const float* feat      = (const float*)d_in[5];
    const float* pseudo    = (const float*)d_in[6];
    const float* W_fc      = (const float*)d_in[7];
    const float* mu        = (const float*)d_in[8];
    const float* inv_sigma = (const float*)d_in[9];
    const float* bias      = (const float*)d_in[10];
    float* out = (float*)d_out;

    const int N = in_sizes[0] - 1;        // 50000
    char*  nfq = (char*)d_ws;             // i8 [N][256] = 12.8 MB
    float* sc  = (float*)(nfq + (size_t)N * 256);  // f32 [N][4] = 0.8 MB
    f16*   Wp  = (f16*)d_out;             // 128 KB overlay; edge rewrites
                                          // all of d_out afterwards

    hipLaunchKernelGGL(convert_W, dim3(64), dim3(256), 0, stream, W_fc, Wp);

    hipLaunchKernelGGL(gemm_fused, dim3((N + 63) / 64), dim3(256), 0, stream,
                       feat, Wp, nfq, sc, N);

    // 4 waves/block, 2 nodes/wave -> 8 nodes/block
    hipLaunchKernelGGL(edge_aggregate, dim3((N + 7) / 8), dim3(256), 0, stream,
                       rowptr, colind, pseudo, nfq, sc, mu, inv_sigma, bias, out, N);
}